// Round 11
// baseline (195.621 us; speedup 1.0000x reference)
//
#include <hip/hip_runtime.h>
#include <hip/hip_bf16.h>
#include <stdint.h>

#define D_MODEL 1024
#define NHEAD   16
#define HDIM    64
#define BATCH   4
#define SEQ     2048
#define NTOK    (BATCH*SEQ)   // 8192

typedef __bf16          b16x8 __attribute__((ext_vector_type(8)));
typedef unsigned short  u16x8 __attribute__((ext_vector_type(8)));
typedef unsigned short  u16x4 __attribute__((ext_vector_type(4)));
typedef float           f32x4 __attribute__((ext_vector_type(4)));

__device__ __forceinline__ unsigned short f2b(float f) {
  union { float f; uint32_t u; } c; c.f = f;
  return (unsigned short)((c.u + 0x7FFFu + ((c.u >> 16) & 1u)) >> 16);
}

// packed 2xf32 -> 2xbf16 (attn only)
__device__ __forceinline__ uint32_t cvtpk(float lo, float hi) {
  uint32_t r;
  asm("v_cvt_pk_bf16_f32 %0, %1, %2" : "=v"(r) : "v"(lo), "v"(hi));
  return r;
}

// ---------------- fused QKV projection GEMM ----------------
// EXACT restore of the round-2 proj (fastest measured: ~63-72us by
// subtraction in r1/r2). 40-short padded LDS pitch, launch_bounds(256,2),
// tid>>3 staging (4 rows x u16x4 writes), prefetch issued BEFORE the
// barrier (VGPR-destined loads don't drain at s_barrier; the use-site
// stage at loop bottom gives full compute cover), f2b conversions.
// Changes vs r2: Q scale folds log2(e) (exp2 softmax); everything else same.
__global__ __launch_bounds__(256, 2)
void proj_gemm_kernel(const float* __restrict__ q, const float* __restrict__ k,
                      const float* __restrict__ v, const float* __restrict__ Wq,
                      const float* __restrict__ Wk, const float* __restrict__ Wv,
                      unsigned short* __restrict__ qp, unsigned short* __restrict__ kp,
                      unsigned short* __restrict__ vt) {
  __shared__ unsigned short As[2][128 * 40];   // +8 pad
  __shared__ unsigned short Bs[2][128 * 40];

  int bid = blockIdx.x;
  int swz = (bid & 7) * 192 + (bid >> 3);      // bijective XCD swizzle, 1536 % 8 == 0
  int which = swz >> 9;                        // 0..2
  int rr = swz & 511;
  int tm = rr >> 3, tn = rr & 7;

  const float* X = (which == 0) ? q : ((which == 1) ? k : v);
  const float* W = (which == 0) ? Wq : ((which == 1) ? Wk : Wv);

  int tid  = threadIdx.x;
  int lane = tid & 63;
  int w    = tid >> 6;
  int wr   = (w >> 1) * 64;   // wave quadrant in 128x128 tile
  int wc   = (w & 1) * 64;

  f32x4 acc[4][4];
#pragma unroll
  for (int m = 0; m < 4; m++)
#pragma unroll
    for (int n = 0; n < 4; n++) acc[m][n] = (f32x4){0.f, 0.f, 0.f, 0.f};

  int srow = tid >> 3;   // 0..31
  int sseg = tid & 7;    // 0..7  (8 fp32-quads cover K=32)
  const float* Ag = X + (size_t)(tm * 128 + srow) * D_MODEL + sseg * 4;
  const float* Bg = W + (size_t)(tn * 128 + srow) * D_MODEL + sseg * 4;

  f32x4 ra[4], rb[4];
#pragma unroll
  for (int p = 0; p < 4; p++) {
    ra[p] = *(const f32x4*)(Ag + (size_t)p * 32 * D_MODEL);
    rb[p] = *(const f32x4*)(Bg + (size_t)p * 32 * D_MODEL);
  }
#pragma unroll
  for (int p = 0; p < 4; p++) {            // stage tile 0
    u16x4 ta, tb;
#pragma unroll
    for (int i = 0; i < 4; i++) { ta[i] = f2b(ra[p][i]); tb[i] = f2b(rb[p][i]); }
    *(u16x4*)&As[0][(p * 32 + srow) * 40 + sseg * 4] = ta;
    *(u16x4*)&Bs[0][(p * 32 + srow) * 40 + sseg * 4] = tb;
  }

  for (int kt = 0; kt < 32; kt++) {
    if (kt < 31) {                         // prefetch next K-slab into regs
#pragma unroll
      for (int p = 0; p < 4; p++) {
        ra[p] = *(const f32x4*)(Ag + (size_t)p * 32 * D_MODEL + (kt + 1) * 32);
        rb[p] = *(const f32x4*)(Bg + (size_t)p * 32 * D_MODEL + (kt + 1) * 32);
      }
    }
    __syncthreads();                       // tile kt visible to all waves
    const unsigned short* Ab = As[kt & 1];
    const unsigned short* Bb = Bs[kt & 1];
    int koff = (lane >> 4) * 8;
    u16x8 af[4], bf[4];
#pragma unroll
    for (int m = 0; m < 4; m++)
      af[m] = *(const u16x8*)&Ab[(wr + m * 16 + (lane & 15)) * 40 + koff];
#pragma unroll
    for (int n = 0; n < 4; n++)
      bf[n] = *(const u16x8*)&Bb[(wc + n * 16 + (lane & 15)) * 40 + koff];
#pragma unroll
    for (int m = 0; m < 4; m++)
#pragma unroll
      for (int n = 0; n < 4; n++)
        acc[m][n] = __builtin_amdgcn_mfma_f32_16x16x32_bf16(
            __builtin_bit_cast(b16x8, af[m]), __builtin_bit_cast(b16x8, bf[n]),
            acc[m][n], 0, 0, 0);
    if (kt < 31) {                         // stage tile kt+1 into other buffer
      int nb = (kt + 1) & 1;
#pragma unroll
      for (int p = 0; p < 4; p++) {
        u16x4 ta, tb;
#pragma unroll
        for (int i = 0; i < 4; i++) { ta[i] = f2b(ra[p][i]); tb[i] = f2b(rb[p][i]); }
        *(u16x4*)&As[nb][(p * 32 + srow) * 40 + sseg * 4] = ta;
        *(u16x4*)&Bs[nb][(p * 32 + srow) * 40 + sseg * 4] = tb;
      }
    }
  }

  // epilogue: C/D frag layout: row = (lane>>4)*4+j, col = lane&15
  int cbase = tn * 128 + wc;
  int rbase = tm * 128 + wr;
  if (which < 2) {
    unsigned short* OutP = (which == 0) ? qp : kp;
    // Q: fold 1/sqrt(Dh) AND log2(e) so attention uses native exp2
    float scale = (which == 0) ? 0.18033688f : 1.0f;
#pragma unroll
    for (int m = 0; m < 4; m++)
#pragma unroll
      for (int n = 0; n < 4; n++) {
        int e = cbase + n * 16 + (lane & 15);
        int h = e >> 6, dh = e & 63;
#pragma unroll
        for (int j = 0; j < 4; j++) {
          int i = rbase + m * 16 + (lane >> 4) * 4 + j;
          int b = i >> 11, s = i & 2047;
          OutP[(((size_t)(b * NHEAD + h)) * SEQ + s) * HDIM + dh] =
              f2b(acc[m][n][j] * scale);
        }
      }
  } else {  // V: write transposed (b,h,dh,s); 4 consecutive s per lane -> 8B store
#pragma unroll
    for (int m = 0; m < 4; m++)
#pragma unroll
      for (int n = 0; n < 4; n++) {
        int e = cbase + n * 16 + (lane & 15);
        int h = e >> 6, dh = e & 63;
        int i0 = rbase + m * 16 + (lane >> 4) * 4;
        int b = i0 >> 11, s0 = i0 & 2047;
        u16x4 pk;
#pragma unroll
        for (int j = 0; j < 4; j++) pk[j] = f2b(acc[m][n][j]);
        *(u16x4*)&vt[(((size_t)(b * NHEAD + h)) * HDIM + dh) * SEQ + s0] = pk;
      }
  }
}

// ---------------- flash attention v4: 32 q-rows/wave, max-free softmax ----------------
// (unchanged from r10; stable ~65us)
#define KVB 64
__global__ __launch_bounds__(256, 3)
void attn_kernel(const unsigned short* __restrict__ qp,
                 const unsigned short* __restrict__ kp,
                 const unsigned short* __restrict__ vt,
                 float* __restrict__ out) {
  __shared__ __align__(16) char lds[2][16384];  // per buf: K tile 8KB | V tile 8KB

  int bid = blockIdx.x;
  int swz = (bid & 7) * 128 + (bid >> 3);  // bijective XCD swizzle, 1024 % 8 == 0
  int bh = swz >> 4;   // 0..63
  int qb = swz & 15;

  int tid  = threadIdx.x;
  int lane = tid & 63;
  int w    = tid >> 6;
  int g    = lane >> 4;
  int c    = lane & 15;
  int chi  = c & 7;

  const unsigned short* Kg = kp + (size_t)bh * SEQ * HDIM;
  const unsigned short* Vg = vt + (size_t)bh * HDIM * SEQ;

  // ---- Q fragments (B-operand): qf[qg][h], q-rows q0+qg*16+c ----
  int q0 = qb * 128 + w * 32;
  u16x8 qf[2][2];
#pragma unroll
  for (int qg = 0; qg < 2; qg++)
#pragma unroll
    for (int h = 0; h < 2; h++)
      qf[qg][h] = *(const u16x8*)&qp[((size_t)bh * SEQ + q0 + qg * 16 + c) * HDIM + h * 32 + g * 8];

  f32x4 o[4][2];
#pragma unroll
  for (int d = 0; d < 4; d++)
#pragma unroll
    for (int qg = 0; qg < 2; qg++) o[d][qg] = (f32x4){0.f, 0.f, 0.f, 0.f};
  float l[2] = {0.f, 0.f};

  // ---- hoisted LDS byte offsets ----
  int koffA = c * 128 + ((g * 16) ^ (chi << 4));
  int koffB = c * 128 + (((64 + g * 16)) ^ (chi << 4));
  int voff[2][2];
#pragma unroll
  for (int w2 = 0; w2 < 2; w2++) {
    int b0 = w2 * 64 + g * 8;
    voff[w2][0] = 8192 + c * 128 + ((((b0      >> 4) ^ chi) << 4) + (b0 & 15));
    voff[w2][1] = 8192 + c * 128 + (((((b0+32) >> 4) ^ chi) << 4) + (b0 & 15));
  }
  // staging (rows arow, arow+32; (arow+32)&7 == arow&7 so +4096 immediate works)
  int arow = tid >> 3, aseg = tid & 7;
  int kwo = arow * 128 + ((aseg * 16) ^ ((arow & 7) << 4));
  int vwo = 8192 + kwo;

  char* cur = lds[0];
  char* nxt = lds[1];

  // preload tile 0 -> regs -> LDS buf0
  u16x8 kreg[2], vreg[2];
  kreg[0] = *(const u16x8*)&Kg[(size_t)arow * HDIM + aseg * 8];
  kreg[1] = *(const u16x8*)&Kg[(size_t)(arow + 32) * HDIM + aseg * 8];
  vreg[0] = *(const u16x8*)&Vg[(size_t)arow * SEQ + aseg * 8];
  vreg[1] = *(const u16x8*)&Vg[(size_t)(arow + 32) * SEQ + aseg * 8];
  *(u16x8*)(cur + kwo)        = kreg[0];
  *(u16x8*)(cur + kwo + 4096) = kreg[1];
  *(u16x8*)(cur + vwo)        = vreg[0];
  *(u16x8*)(cur + vwo + 4096) = vreg[1];
  __syncthreads();

  for (int t = 0; t < SEQ / KVB; t++) {
    if (t < SEQ / KVB - 1) {       // issue next-tile global loads early (hide under compute)
      int kv1 = (t + 1) * KVB;
      kreg[0] = *(const u16x8*)&Kg[(size_t)(kv1 + arow) * HDIM + aseg * 8];
      kreg[1] = *(const u16x8*)&Kg[(size_t)(kv1 + arow + 32) * HDIM + aseg * 8];
      vreg[0] = *(const u16x8*)&Vg[(size_t)arow * SEQ + kv1 + aseg * 8];
      vreg[1] = *(const u16x8*)&Vg[(size_t)(arow + 32) * SEQ + kv1 + aseg * 8];
    }

    // ---- S^T = K Q^T : sf[st][qg][j] = S[key st*16+4g+j][q qg*16+c] ----
    f32x4 sf[4][2];
#pragma unroll
    for (int st = 0; st < 4; st++) {
      u16x8 kf0 = *(const u16x8*)(cur + koffA + st * 2048);
      u16x8 kf1 = *(const u16x8*)(cur + koffB + st * 2048);
#pragma unroll
      for (int qg = 0; qg < 2; qg++) {
        sf[st][qg] = __builtin_amdgcn_mfma_f32_16x16x32_bf16(
            __builtin_bit_cast(b16x8, kf0), __builtin_bit_cast(b16x8, qf[qg][0]),
            (f32x4){0.f, 0.f, 0.f, 0.f}, 0, 0, 0);
        sf[st][qg] = __builtin_amdgcn_mfma_f32_16x16x32_bf16(
            __builtin_bit_cast(b16x8, kf1), __builtin_bit_cast(b16x8, qf[qg][1]),
            sf[st][qg], 0, 0, 0);
      }
    }

    // ---- P = exp2(S~) (bounded, no max needed); pack to bf16 lane-local ----
    union { uint32_t u[4]; u16x8 v; } pb[2][2];   // [w2][qg]
#pragma unroll
    for (int qg = 0; qg < 2; qg++) {
      float p[4][4];
#pragma unroll
      for (int st = 0; st < 4; st++)
#pragma unroll
        for (int j = 0; j < 4; j++) p[st][j] = exp2f(sf[st][qg][j]);
      float s01 = ((p[0][0] + p[0][1]) + (p[0][2] + p[0][3])) +
                  ((p[1][0] + p[1][1]) + (p[1][2] + p[1][3]));
      float s23 = ((p[2][0] + p[2][1]) + (p[2][2] + p[2][3])) +
                  ((p[3][0] + p[3][1]) + (p[3][2] + p[3][3]));
      l[qg] += s01 + s23;
#pragma unroll
      for (int w2 = 0; w2 < 2; w2++) {
        pb[w2][qg].u[0] = cvtpk(p[2*w2][0],   p[2*w2][1]);
        pb[w2][qg].u[1] = cvtpk(p[2*w2][2],   p[2*w2][3]);
        pb[w2][qg].u[2] = cvtpk(p[2*w2+1][0], p[2*w2+1][1]);
        pb[w2][qg].u[3] = cvtpk(p[2*w2+1][2], p[2*w2+1][3]);
      }
    }

    // ---- O^T += V^T P^T (V frags read once, reused across qg) ----
#pragma unroll
    for (int w2 = 0; w2 < 2; w2++)
#pragma unroll
      for (int d = 0; d < 4; d++) {
        union { u16x4 h[2]; u16x8 v; } afu;
        afu.h[0] = *(const u16x4*)(cur + voff[w2][0] + d * 2048);
        afu.h[1] = *(const u16x4*)(cur + voff[w2][1] + d * 2048);
#pragma unroll
        for (int qg = 0; qg < 2; qg++)
          o[d][qg] = __builtin_amdgcn_mfma_f32_16x16x32_bf16(
              __builtin_bit_cast(b16x8, afu.v), __builtin_bit_cast(b16x8, pb[w2][qg].v),
              o[d][qg], 0, 0, 0);
      }

    if (t < SEQ / KVB - 1) {       // stage t+1 into other buffer
      *(u16x8*)(nxt + kwo)        = kreg[0];
      *(u16x8*)(nxt + kwo + 4096) = kreg[1];
      *(u16x8*)(nxt + vwo)        = vreg[0];
      *(u16x8*)(nxt + vwo + 4096) = vreg[1];
    }
    __syncthreads();
    char* tmp = cur; cur = nxt; nxt = tmp;
  }

  // ---- epilogue: reduce l across the 4 key-groups, normalize, store ----
#pragma unroll
  for (int qg = 0; qg < 2; qg++) {
    l[qg] += __shfl_xor(l[qg], 16);
    l[qg] += __shfl_xor(l[qg], 32);
  }
#pragma unroll
  for (int qg = 0; qg < 2; qg++) {
    float inv = 1.f / l[qg];
    float* orow = out + ((size_t)bh * SEQ + q0 + qg * 16 + c) * HDIM;
#pragma unroll
    for (int d = 0; d < 4; d++) {
      f32x4 val;
#pragma unroll
      for (int j = 0; j < 4; j++) val[j] = o[d][qg][j] * inv;
      *(f32x4*)(orow + d * 16 + g * 4) = val;
    }
  }
}

extern "C" void kernel_launch(void* const* d_in, const int* in_sizes, int n_in,
                              void* d_out, int out_size, void* d_ws, size_t ws_size,
                              hipStream_t stream) {
  const float* q  = (const float*)d_in[0];
  const float* k  = (const float*)d_in[1];
  const float* v  = (const float*)d_in[2];
  const float* Wq = (const float*)d_in[3];
  const float* Wk = (const float*)d_in[4];
  const float* Wv = (const float*)d_in[5];

  unsigned short* qp = (unsigned short*)d_ws;                 // (B,H,S,Dh) bf16
  unsigned short* kp = qp + (size_t)NTOK * D_MODEL;           // (B,H,S,Dh) bf16
  unsigned short* vt = kp + (size_t)NTOK * D_MODEL;           // (B,H,Dh,S) bf16
  float* out = (float*)d_out;

  hipLaunchKernelGGL(proj_gemm_kernel, dim3(1536), dim3(256), 0, stream,
                     q, k, v, Wq, Wk, Wv, qp, kp, vt);
  hipLaunchKernelGGL(attn_kernel, dim3(1024), dim3(256), 0, stream,
                     qp, kp, vt, out);
}

// Round 12
// 180.057 us; speedup vs baseline: 1.0864x; 1.0864x over previous
//
#include <hip/hip_runtime.h>
#include <hip/hip_bf16.h>
#include <stdint.h>

#define D_MODEL 1024
#define NHEAD   16
#define HDIM    64
#define BATCH   4
#define SEQ     2048
#define NTOK    (BATCH*SEQ)   // 8192

typedef __bf16          b16x8 __attribute__((ext_vector_type(8)));
typedef unsigned short  u16x8 __attribute__((ext_vector_type(8)));
typedef unsigned short  u16x4 __attribute__((ext_vector_type(4)));
typedef float           f32x4 __attribute__((ext_vector_type(4)));

__device__ __forceinline__ unsigned short f2b(float f) {
  union { float f; uint32_t u; } c; c.f = f;
  return (unsigned short)((c.u + 0x7FFFu + ((c.u >> 16) & 1u)) >> 16);
}

// packed 2xf32 -> 2xbf16 (attn P-pack only)
__device__ __forceinline__ uint32_t cvtpk(float lo, float hi) {
  uint32_t r;
  asm("v_cvt_pk_bf16_f32 %0, %1, %2" : "=v"(r) : "v"(lo), "v"(hi));
  return r;
}

// fp32x8 -> bf16x8 via NATIVE casts (compiler emits v_cvt_pk_bf16_f32 pairs;
// m240: don't hand-write the asm, the compiler handles paired converts)
__device__ __forceinline__ b16x8 cv8(f32x4 a, f32x4 b) {
  b16x8 r;
#pragma unroll
  for (int i = 0; i < 4; i++) { r[i] = (__bf16)a[i]; r[i + 4] = (__bf16)b[i]; }
  return r;
}

// async global->LDS, 16B per lane; dest = wave-uniform base + lane*16
__device__ __forceinline__ void glds16(const void* g, void* l) {
  __builtin_amdgcn_global_load_lds(
      (const __attribute__((address_space(1))) unsigned int*)g,
      (__attribute__((address_space(3))) unsigned int*)l, 16, 0, 0);
}

// ---------------- W pack: fp32 -> bf16 in pre-swizzled LDS-image layout ----------------
// One block per (which, tn, kt): emits the exact 8KB B-tile image that
// proj_gemm DMA-copies linearly via global_load_lds (rule #21: linear dest +
// pre-swizzled source + swizzled ds_read = same involution). Verified r8.
__global__ __launch_bounds__(256, 8)
void wpack_kernel(const float* __restrict__ Wq, const float* __restrict__ Wk,
                  const float* __restrict__ Wv, unsigned short* __restrict__ wsp) {
  int bid = blockIdx.x;            // 768 = 3(which) * 8(tn) * 32(kt)
  int which = bid >> 8;
  int tn = (bid >> 5) & 7;
  int kt = bid & 31;
  const float* W = (which == 0) ? Wq : ((which == 1) ? Wk : Wv);
  int t = threadIdx.x;
  int r = t >> 1;                  // tile row 0..127
  int sw0 = (t & 1) * 2;           // swizzled slot pair {0,1} or {2,3}
  char* dst = (char*)wsp + (size_t)bid * 8192 + t * 32;
  const float* src = W + (size_t)(tn * 128 + r) * D_MODEL + kt * 32;
#pragma unroll
  for (int i = 0; i < 2; i++) {
    int s = (sw0 + i) ^ ((r >> 1) & 3);   // content chunk for this slot
    f32x4 a = *(const f32x4*)(src + s * 8);
    f32x4 b = *(const f32x4*)(src + s * 8 + 4);
    u16x8 pk;
#pragma unroll
    for (int j = 0; j < 4; j++) { pk[j] = f2b(a[j]); pk[j + 4] = f2b(b[j]); }
    *(u16x8*)(dst + i * 16) = pk;
  }
}

// ---------------- fused QKV projection GEMM (round 12: full DMA staging) ----------------
// C = X(8192x1024) @ W^T; BM=BN=128, BK=32, 256 threads / 4 waves.
// A (fp32 X): global_load_lds direct, per-lane source pre-swizzled with
//   chunk^(row&7) inside each 128B row (coalescing preserved; swizzled reads
//   2 lanes/bank = free). Converted to bf16 at fragment read via native casts.
// B (W): pre-packed bf16 image (wpack), linear DMA copy.
// Loop body: barrier -> issue 6 glds into other buf -> 12 ds_read_b128 ->
// 16 MFMA. No ds_write, no reg staging; glds drain at NEXT barrier (full
// K-step of cover). LDS 48KB -> 3 blocks/CU.
__global__ __launch_bounds__(256, 3)
void proj_gemm_kernel(const float* __restrict__ q, const float* __restrict__ k,
                      const float* __restrict__ v, const unsigned short* __restrict__ wsp,
                      unsigned short* __restrict__ qp, unsigned short* __restrict__ kp,
                      unsigned short* __restrict__ vt) {
  __shared__ __align__(16) char lds[2][24576];   // per buf: A 16KB fp32 | B 8KB bf16

  int bid = blockIdx.x;
  int swz = (bid & 7) * 192 + (bid >> 3);      // bijective XCD swizzle, 1536 % 8 == 0
  int which = swz >> 9;                        // 0..2
  int rr = swz & 511;
  int tm = rr >> 3, tn = rr & 7;

  const float* X = (which == 0) ? q : ((which == 1) ? k : v);
  const char* Bpack = (const char*)wsp + (size_t)((which * 8 + tn) * 32) * 8192;

  int tid  = threadIdx.x;
  int lane = tid & 63;
  int w    = tid >> 6;
  int g    = lane >> 4;
  int c    = lane & 15;
  int chi  = c & 7;
  int wr   = (w >> 1) * 64;
  int wc   = (w & 1) * 64;

  f32x4 acc[4][4];
#pragma unroll
  for (int m = 0; m < 4; m++)
#pragma unroll
    for (int n = 0; n < 4; n++) acc[m][n] = (f32x4){0.f, 0.f, 0.f, 0.f};

  // A DMA: wave w covers rows [w*32, w*32+32), 4 glds16 of 1KB each.
  // lane -> LDS slot lane*16 within its 1KB group (8 rows x 128B);
  // source chunk pre-swizzled: content chunk = (lane&7) ^ (row&7).
  int arowl = lane >> 3;                       // 0..7 (row within 8-row group)
  int aswz  = ((lane & 7) ^ arowl) << 4;       // source chunk byte offset
  const char* Asrc = (const char*)(X + (size_t)(tm * 128 + w * 32 + arowl) * D_MODEL) + aswz;
  // B DMA: linear copy of pre-packed image; wave w covers bytes [w*2048, +2048)
  const char* Bsrc = Bpack + w * 2048 + lane * 16;

  // A frag reads (fp32): row wr+m*16+c, content chunks 2g, 2g+1 at swizzled slots
  int aoff0 = (wr + c) * 128 + ((2 * g    ^ chi) << 4);   // + m*2048
  int aoff1 = (wr + c) * 128 + (((2*g+1) ^ chi) << 4);    // + m*2048
  // B frag reads (bf16): r8-verified swizzle
  int rboff = 16384 + (wc + c) * 64 + ((g ^ ((c >> 1) & 3)) << 4);  // + n*1024

  // ---- prologue: DMA tile 0 into buf0 ----
#pragma unroll
  for (int i = 0; i < 4; i++)
    glds16(Asrc + (size_t)i * 8 * D_MODEL * 4, lds[0] + w * 4096 + i * 1024);
  glds16(Bsrc,        lds[0] + 16384 + w * 2048);
  glds16(Bsrc + 1024, lds[0] + 16384 + w * 2048 + 1024);

  for (int kt = 0; kt < 32; kt++) {
    __syncthreads();                 // drains glds for tile kt (and frees other buf)
    if (kt < 31) {                   // DMA tile kt+1 into other buffer (covered by compute)
      char* nb = lds[(kt + 1) & 1];
#pragma unroll
      for (int i = 0; i < 4; i++)
        glds16(Asrc + (size_t)i * 8 * D_MODEL * 4 + (kt + 1) * 128, nb + w * 4096 + i * 1024);
      glds16(Bsrc + (size_t)(kt + 1) * 8192,        nb + 16384 + w * 2048);
      glds16(Bsrc + (size_t)(kt + 1) * 8192 + 1024, nb + 16384 + w * 2048 + 1024);
    }
    const char* buf = lds[kt & 1];
    b16x8 af[4];
    u16x8 bf[4];
#pragma unroll
    for (int m = 0; m < 4; m++) {
      f32x4 a0 = *(const f32x4*)(buf + aoff0 + m * 2048);
      f32x4 a1 = *(const f32x4*)(buf + aoff1 + m * 2048);
      af[m] = cv8(a0, a1);
    }
#pragma unroll
    for (int n = 0; n < 4; n++)
      bf[n] = *(const u16x8*)(buf + rboff + n * 1024);
#pragma unroll
    for (int m = 0; m < 4; m++)
#pragma unroll
      for (int n = 0; n < 4; n++)
        acc[m][n] = __builtin_amdgcn_mfma_f32_16x16x32_bf16(
            af[m], __builtin_bit_cast(b16x8, bf[n]), acc[m][n], 0, 0, 0);
  }

  // epilogue: C/D frag layout: row = g*4+j, col = c
  int cbase = tn * 128 + wc;
  int rbase = tm * 128 + wr;
  if (which < 2) {
    unsigned short* OutP = (which == 0) ? qp : kp;
    // Q: fold 1/sqrt(Dh) AND log2(e) so attention uses native exp2
    float scale = (which == 0) ? 0.18033688f : 1.0f;
#pragma unroll
    for (int m = 0; m < 4; m++)
#pragma unroll
      for (int n = 0; n < 4; n++) {
        int e = cbase + n * 16 + c;
        int h = e >> 6, dh = e & 63;
#pragma unroll
        for (int j = 0; j < 4; j++) {
          int i = rbase + m * 16 + g * 4 + j;
          int b = i >> 11, s = i & 2047;
          OutP[(((size_t)(b * NHEAD + h)) * SEQ + s) * HDIM + dh] =
              f2b(acc[m][n][j] * scale);
        }
      }
  } else {  // V: write transposed (b,h,dh,s); 4 consecutive s per lane -> 8B store
#pragma unroll
    for (int m = 0; m < 4; m++)
#pragma unroll
      for (int n = 0; n < 4; n++) {
        int e = cbase + n * 16 + c;
        int h = e >> 6, dh = e & 63;
        int i0 = rbase + m * 16 + g * 4;
        int b = i0 >> 11, s0 = i0 & 2047;
        u16x4 pk;
#pragma unroll
        for (int j = 0; j < 4; j++) pk[j] = f2b(acc[m][n][j]);
        *(u16x4*)&vt[(((size_t)(b * NHEAD + h)) * HDIM + dh) * SEQ + s0] = pk;
      }
  }
}

// ---------------- flash attention v4: 32 q-rows/wave, max-free softmax ----------------
// (unchanged; stable ~65us, ~42% of MFMA peak)
#define KVB 64
__global__ __launch_bounds__(256, 3)
void attn_kernel(const unsigned short* __restrict__ qp,
                 const unsigned short* __restrict__ kp,
                 const unsigned short* __restrict__ vt,
                 float* __restrict__ out) {
  __shared__ __align__(16) char lds[2][16384];  // per buf: K tile 8KB | V tile 8KB

  int bid = blockIdx.x;
  int swz = (bid & 7) * 128 + (bid >> 3);  // bijective XCD swizzle, 1024 % 8 == 0
  int bh = swz >> 4;   // 0..63
  int qb = swz & 15;

  int tid  = threadIdx.x;
  int lane = tid & 63;
  int w    = tid >> 6;
  int g    = lane >> 4;
  int c    = lane & 15;
  int chi  = c & 7;

  const unsigned short* Kg = kp + (size_t)bh * SEQ * HDIM;
  const unsigned short* Vg = vt + (size_t)bh * HDIM * SEQ;

  // ---- Q fragments (B-operand): qf[qg][h], q-rows q0+qg*16+c ----
  int q0 = qb * 128 + w * 32;
  u16x8 qf[2][2];
#pragma unroll
  for (int qg = 0; qg < 2; qg++)
#pragma unroll
    for (int h = 0; h < 2; h++)
      qf[qg][h] = *(const u16x8*)&qp[((size_t)bh * SEQ + q0 + qg * 16 + c) * HDIM + h * 32 + g * 8];

  f32x4 o[4][2];
#pragma unroll
  for (int d = 0; d < 4; d++)
#pragma unroll
    for (int qg = 0; qg < 2; qg++) o[d][qg] = (f32x4){0.f, 0.f, 0.f, 0.f};
  float l[2] = {0.f, 0.f};

  // ---- hoisted LDS byte offsets ----
  int koffA = c * 128 + ((g * 16) ^ (chi << 4));
  int koffB = c * 128 + (((64 + g * 16)) ^ (chi << 4));
  int voff[2][2];
#pragma unroll
  for (int w2 = 0; w2 < 2; w2++) {
    int b0 = w2 * 64 + g * 8;
    voff[w2][0] = 8192 + c * 128 + ((((b0      >> 4) ^ chi) << 4) + (b0 & 15));
    voff[w2][1] = 8192 + c * 128 + (((((b0+32) >> 4) ^ chi) << 4) + (b0 & 15));
  }
  // staging (rows arow, arow+32; (arow+32)&7 == arow&7 so +4096 immediate works)
  int arow = tid >> 3, aseg = tid & 7;
  int kwo = arow * 128 + ((aseg * 16) ^ ((arow & 7) << 4));
  int vwo = 8192 + kwo;

  char* cur = lds[0];
  char* nxt = lds[1];

  // preload tile 0 -> regs -> LDS buf0
  u16x8 kreg[2], vreg[2];
  kreg[0] = *(const u16x8*)&Kg[(size_t)arow * HDIM + aseg * 8];
  kreg[1] = *(const u16x8*)&Kg[(size_t)(arow + 32) * HDIM + aseg * 8];
  vreg[0] = *(const u16x8*)&Vg[(size_t)arow * SEQ + aseg * 8];
  vreg[1] = *(const u16x8*)&Vg[(size_t)(arow + 32) * SEQ + aseg * 8];
  *(u16x8*)(cur + kwo)        = kreg[0];
  *(u16x8*)(cur + kwo + 4096) = kreg[1];
  *(u16x8*)(cur + vwo)        = vreg[0];
  *(u16x8*)(cur + vwo + 4096) = vreg[1];
  __syncthreads();

  for (int t = 0; t < SEQ / KVB; t++) {
    if (t < SEQ / KVB - 1) {       // issue next-tile global loads early (hide under compute)
      int kv1 = (t + 1) * KVB;
      kreg[0] = *(const u16x8*)&Kg[(size_t)(kv1 + arow) * HDIM + aseg * 8];
      kreg[1] = *(const u16x8*)&Kg[(size_t)(kv1 + arow + 32) * HDIM + aseg * 8];
      vreg[0] = *(const u16x8*)&Vg[(size_t)arow * SEQ + kv1 + aseg * 8];
      vreg[1] = *(const u16x8*)&Vg[(size_t)(arow + 32) * SEQ + kv1 + aseg * 8];
    }

    // ---- S^T = K Q^T : sf[st][qg][j] = S[key st*16+4g+j][q qg*16+c] ----
    f32x4 sf[4][2];
#pragma unroll
    for (int st = 0; st < 4; st++) {
      u16x8 kf0 = *(const u16x8*)(cur + koffA + st * 2048);
      u16x8 kf1 = *(const u16x8*)(cur + koffB + st * 2048);
#pragma unroll
      for (int qg = 0; qg < 2; qg++) {
        sf[st][qg] = __builtin_amdgcn_mfma_f32_16x16x32_bf16(
            __builtin_bit_cast(b16x8, kf0), __builtin_bit_cast(b16x8, qf[qg][0]),
            (f32x4){0.f, 0.f, 0.f, 0.f}, 0, 0, 0);
        sf[st][qg] = __builtin_amdgcn_mfma_f32_16x16x32_bf16(
            __builtin_bit_cast(b16x8, kf1), __builtin_bit_cast(b16x8, qf[qg][1]),
            sf[st][qg], 0, 0, 0);
      }
    }

    // ---- P = exp2(S~) (bounded, no max needed); pack to bf16 lane-local ----
    union { uint32_t u[4]; u16x8 v; } pb[2][2];   // [w2][qg]
#pragma unroll
    for (int qg = 0; qg < 2; qg++) {
      float p[4][4];
#pragma unroll
      for (int st = 0; st < 4; st++)
#pragma unroll
        for (int j = 0; j < 4; j++) p[st][j] = exp2f(sf[st][qg][j]);
      float s01 = ((p[0][0] + p[0][1]) + (p[0][2] + p[0][3])) +
                  ((p[1][0] + p[1][1]) + (p[1][2] + p[1][3]));
      float s23 = ((p[2][0] + p[2][1]) + (p[2][2] + p[2][3])) +
                  ((p[3][0] + p[3][1]) + (p[3][2] + p[3][3]));
      l[qg] += s01 + s23;
#pragma unroll
      for (int w2 = 0; w2 < 2; w2++) {
        pb[w2][qg].u[0] = cvtpk(p[2*w2][0],   p[2*w2][1]);
        pb[w2][qg].u[1] = cvtpk(p[2*w2][2],   p[2*w2][3]);
        pb[w2][qg].u[2] = cvtpk(p[2*w2+1][0], p[2*w2+1][1]);
        pb[w2][qg].u[3] = cvtpk(p[2*w2+1][2], p[2*w2+1][3]);
      }
    }

    // ---- O^T += V^T P^T (V frags read once, reused across qg) ----
#pragma unroll
    for (int w2 = 0; w2 < 2; w2++)
#pragma unroll
      for (int d = 0; d < 4; d++) {
        union { u16x4 h[2]; u16x8 v; } afu;
        afu.h[0] = *(const u16x4*)(cur + voff[w2][0] + d * 2048);
        afu.h[1] = *(const u16x4*)(cur + voff[w2][1] + d * 2048);
#pragma unroll
        for (int qg = 0; qg < 2; qg++)
          o[d][qg] = __builtin_amdgcn_mfma_f32_16x16x32_bf16(
              __builtin_bit_cast(b16x8, afu.v), __builtin_bit_cast(b16x8, pb[w2][qg].v),
              o[d][qg], 0, 0, 0);
      }

    if (t < SEQ / KVB - 1) {       // stage t+1 into other buffer
      *(u16x8*)(nxt + kwo)        = kreg[0];
      *(u16x8*)(nxt + kwo + 4096) = kreg[1];
      *(u16x8*)(nxt + vwo)        = vreg[0];
      *(u16x8*)(nxt + vwo + 4096) = vreg[1];
    }
    __syncthreads();
    char* tmp = cur; cur = nxt; nxt = tmp;
  }

  // ---- epilogue: reduce l across the 4 key-groups, normalize, store ----
#pragma unroll
  for (int qg = 0; qg < 2; qg++) {
    l[qg] += __shfl_xor(l[qg], 16);
    l[qg] += __shfl_xor(l[qg], 32);
  }
#pragma unroll
  for (int qg = 0; qg < 2; qg++) {
    float inv = 1.f / l[qg];
    float* orow = out + ((size_t)bh * SEQ + q0 + qg * 16 + c) * HDIM;
#pragma unroll
    for (int d = 0; d < 4; d++) {
      f32x4 val;
#pragma unroll
      for (int j = 0; j < 4; j++) val[j] = o[d][qg][j] * inv;
      *(f32x4*)(orow + d * 16 + g * 4) = val;
    }
  }
}

extern "C" void kernel_launch(void* const* d_in, const int* in_sizes, int n_in,
                              void* d_out, int out_size, void* d_ws, size_t ws_size,
                              hipStream_t stream) {
  const float* q  = (const float*)d_in[0];
  const float* k  = (const float*)d_in[1];
  const float* v  = (const float*)d_in[2];
  const float* Wq = (const float*)d_in[3];
  const float* Wk = (const float*)d_in[4];
  const float* Wv = (const float*)d_in[5];

  unsigned short* qp  = (unsigned short*)d_ws;                // (B,H,S,Dh) bf16
  unsigned short* kp  = qp + (size_t)NTOK * D_MODEL;          // (B,H,S,Dh) bf16
  unsigned short* vt  = kp + (size_t)NTOK * D_MODEL;          // (B,H,Dh,S) bf16
  unsigned short* wsp = vt + (size_t)NTOK * D_MODEL;          // packed W tiles, 6 MB
  float* out = (float*)d_out;

  hipLaunchKernelGGL(wpack_kernel, dim3(768), dim3(256), 0, stream,
                     Wq, Wk, Wv, wsp);
  hipLaunchKernelGGL(proj_gemm_kernel, dim3(1536), dim3(256), 0, stream,
                     q, k, v, wsp, qp, kp, vt);
  hipLaunchKernelGGL(attn_kernel, dim3(1024), dim3(256), 0, stream,
                     qp, kp, vt, out);
}